// Round 2
// baseline (1569.370 us; speedup 1.0000x reference)
//
#include <hip/hip_runtime.h>
#include <hip/hip_bf16.h>
#include <math.h>

#define NB 16
#define NT 4096
#define ND 1024
#define NCC 128
#define LCH 64
#define NCHUNK 64
#define BTROWS 65536

typedef __bf16 v8bf __attribute__((ext_vector_type(8)));
typedef float  v4f  __attribute__((ext_vector_type(4)));

static __device__ __forceinline__ float sig_(float x){ return 1.0f/(1.0f + __expf(-x)); }

static __device__ __forceinline__ v8bf pack8(float4 a, float4 b){
    v8bf v;
    v[0]=(__bf16)a.x; v[1]=(__bf16)a.y; v[2]=(__bf16)a.z; v[3]=(__bf16)a.w;
    v[4]=(__bf16)b.x; v[5]=(__bf16)b.y; v[6]=(__bf16)b.z; v[7]=(__bf16)b.w;
    return v;
}

// ---------------- GEMM1: fused projections x @ [Wq;Wk;Wv;Wg;Wa;Wb]^T ----------------
__global__ __launch_bounds__(256) void k_proj(
    const float* __restrict__ x,
    const float* __restrict__ Wq, const float* __restrict__ bq,
    const float* __restrict__ Wk, const float* __restrict__ bk,
    const float* __restrict__ Wv, const float* __restrict__ bv,
    const float* __restrict__ Wa, const float* __restrict__ ba,
    const float* __restrict__ Wb, const float* __restrict__ bb2,
    const float* __restrict__ Wg, const float* __restrict__ bg,
    float* __restrict__ qb, float* __restrict__ kb, float* __restrict__ vb,
    float* __restrict__ gb, float* __restrict__ ab, float* __restrict__ beb)
{
    __shared__ __attribute__((aligned(16))) __bf16 As[128*40];
    __shared__ __attribute__((aligned(16))) __bf16 Bs[64*40];
    const int tid = threadIdx.x;
    const int m0 = blockIdx.x*128, n0 = blockIdx.y*64;
    const int lane = tid & 63, w = tid >> 6;
    const int q4 = lane >> 4, l16 = lane & 15;

    const int arow = tid >> 1, aseg = tid & 1;
    const int brow = tid >> 2, bseg = tid & 3;
    const float* asrc = x + (size_t)(m0 + arow)*ND;
    const int nrow = n0 + brow;
    const float* bsrc;
    if      (nrow < 128) bsrc = Wq + (size_t)nrow*ND;
    else if (nrow < 256) bsrc = Wk + (size_t)(nrow-128)*ND;
    else if (nrow < 384) bsrc = Wv + (size_t)(nrow-256)*ND;
    else if (nrow < 512) bsrc = Wg + (size_t)(nrow-384)*ND;
    else if (nrow == 512) bsrc = Wa;
    else if (nrow == 513) bsrc = Wb;
    else bsrc = nullptr;

    v4f acc[2][4] = {};

    for (int k0 = 0; k0 < ND; k0 += 32){
        __syncthreads();
        {
            float4 f0 = *(const float4*)(asrc + k0 + aseg*16);
            float4 f1 = *(const float4*)(asrc + k0 + aseg*16 + 4);
            float4 f2 = *(const float4*)(asrc + k0 + aseg*16 + 8);
            float4 f3 = *(const float4*)(asrc + k0 + aseg*16 + 12);
            *(v8bf*)(&As[arow*40 + aseg*16])     = pack8(f0,f1);
            *(v8bf*)(&As[arow*40 + aseg*16 + 8]) = pack8(f2,f3);
        }
        if (bsrc){
            float4 g0 = *(const float4*)(bsrc + k0 + bseg*8);
            float4 g1 = *(const float4*)(bsrc + k0 + bseg*8 + 4);
            *(v8bf*)(&Bs[brow*40 + bseg*8]) = pack8(g0,g1);
        } else {
            *(int4*)(&Bs[brow*40 + bseg*8]) = make_int4(0,0,0,0);
        }
        __syncthreads();
        v8bf af0 = *(const v8bf*)(&As[(w*32 + l16)*40 + q4*8]);
        v8bf af1 = *(const v8bf*)(&As[(w*32 + 16 + l16)*40 + q4*8]);
        #pragma unroll
        for (int nt=0; nt<4; nt++){
            v8bf bf = *(const v8bf*)(&Bs[(nt*16 + l16)*40 + q4*8]);
            acc[0][nt] = __builtin_amdgcn_mfma_f32_16x16x32_bf16(af0, bf, acc[0][nt], 0,0,0);
            acc[1][nt] = __builtin_amdgcn_mfma_f32_16x16x32_bf16(af1, bf, acc[1][nt], 0,0,0);
        }
    }
    #pragma unroll
    for (int mt=0; mt<2; mt++){
        #pragma unroll
        for (int nt=0; nt<4; nt++){
            const int n = n0 + nt*16 + l16;
            #pragma unroll
            for (int r=0;r<4;r++){
                const int m = m0 + w*32 + mt*16 + q4*4 + r;
                const float val = acc[mt][nt][r];
                const size_t mo = (size_t)m*NCC;
                if      (n < 128) qb[mo + n]        = val + bq[n];
                else if (n < 256) kb[mo + (n-128)]  = val + bk[n-128];
                else if (n < 384) vb[mo + (n-256)]  = val + bv[n-256];
                else if (n < 512) gb[mo + (n-384)]  = sig_(val + bg[n-384]);
                else if (n == 512) ab[m]  = sig_(val + ba[0]);
                else if (n == 513) beb[m] = sig_(val + bb2[0]);
            }
        }
    }
}

// ---------------- normalize k rows ----------------
__global__ __launch_bounds__(256) void k_knorm(float* __restrict__ kb){
    const int tid = threadIdx.x;
    const int w = tid >> 6, lane = tid & 63;
    const size_t row = (size_t)blockIdx.x*4 + w;
    float* kr = kb + row*NCC;
    float a = kr[lane], b = kr[lane+64];
    float ss = a*a + b*b;
    #pragma unroll
    for (int m=1;m<64;m<<=1) ss += __shfl_xor(ss, m, 64);
    float inv = 1.0f / fmaxf(sqrtf(ss), 1e-12f);
    kr[lane] = a*inv; kr[lane+64] = b*inv;
}

// ---------------- Phase A: per-chunk precompute (gamma, G, solve U/M, P^T, R) ----------------
__global__ __launch_bounds__(256) void k_phaseA(
    const float* __restrict__ kb, float* __restrict__ vb, float* __restrict__ Mb,
    const float* __restrict__ ab, const float* __restrict__ beb,
    float* __restrict__ lgb, __bf16* __restrict__ PTb, float* __restrict__ Rb)
{
    __shared__ __attribute__((aligned(16))) float Ksh[LCH*132];
    __shared__ __attribute__((aligned(16))) float Ush[LCH*132];
    __shared__ __attribute__((aligned(16))) float Msh[LCH*132];
    __shared__ __attribute__((aligned(16))) float Gsh[LCH*68];
    __shared__ float lgs[LCH], bsh[LCH], esh[LCH], gam[LCH];

    const int tid = threadIdx.x;
    const int b = blockIdx.x >> 6;
    const int c = blockIdx.x & 63;
    const size_t base = (size_t)b*NT + (size_t)c*LCH;

    if (tid < LCH){
        float la = __logf(fmaxf(ab[base+tid], 1e-30f));
        float ps = la;
        #pragma unroll
        for (int off=1; off<64; off<<=1){
            float o = __shfl_up(ps, off, 64);
            if ((tid & 63) >= off) ps += o;
        }
        lgs[tid] = ps;
        bsh[tid] = beb[base+tid];
    }
    {
        const int row = tid >> 2, seg = tid & 3;
        const float* ks = kb + (base+row)*NCC + seg*32;
        const float* vs = vb + (base+row)*NCC + seg*32;
        float* kd = &Ksh[row*132 + seg*32];
        float* vd = &Ush[row*132 + seg*32];
        #pragma unroll
        for (int i=0;i<32;i+=4){
            *(float4*)(kd+i) = *(const float4*)(ks+i);
            *(float4*)(vd+i) = *(const float4*)(vs+i);
        }
    }
    __syncthreads();
    if (tid < LCH){
        lgb[base+tid] = lgs[tid];
        esh[tid] = __expf(lgs[LCH-1] - lgs[tid]);
        gam[tid] = __expf(lgs[tid]);
    }
    // G[t][s] = exp(lg_t - lg_s) * (k_s . k_t), s <= t
    for (int idx = tid; idx < (LCH*(LCH+1))/2; idx += 256){
        int t = (int)((sqrtf(8.f*(float)idx + 1.f) - 1.f)*0.5f);
        while ((t+1)*(t+2)/2 <= idx) t++;
        while (t*(t+1)/2 > idx) t--;
        const int s = idx - (t*(t+1))/2;
        const float* k1 = &Ksh[s*132];
        const float* k2 = &Ksh[t*132];
        float dot = 0.f;
        #pragma unroll 8
        for (int j=0;j<NCC;j+=4){
            float4 u = *(const float4*)(k1+j);
            float4 v = *(const float4*)(k2+j);
            dot += u.x*v.x + u.y*v.y + u.z*v.z + u.w*v.w;
        }
        Gsh[t*68+s] = __expf(lgs[t]-lgs[s])*dot;
    }
    __syncthreads();
    // forward substitution: u_t = b_t(v_t - sum G u_s); m_t = b_t(gam_t k_t - sum G m_s)
    {
        const int half = tid >> 7, cix = tid & 127;
        for (int t=0;t<LCH;t++){
            float acc2 = 0.f;
            if (half == 0){
                for (int s=0;s<t;s++) acc2 += Gsh[t*68+s]*Ush[s*132+cix];
            } else {
                for (int s=0;s<t;s++) acc2 += Gsh[t*68+s]*Msh[s*132+cix];
            }
            float outv;
            if (half == 0) outv = bsh[t]*(Ush[t*132+cix] - acc2);
            else           outv = bsh[t]*(gam[t]*Ksh[t*132+cix] - acc2);
            if (half == 0) Ush[t*132+cix] = outv;
            else           Msh[t*132+cix] = outv;
            __syncthreads();
        }
    }
    // write U (over v) and M to global
    {
        const int row = tid >> 2, seg = tid & 3;
        float* ud = vb + (base+row)*NCC + seg*32;
        float* md = Mb + (base+row)*NCC + seg*32;
        #pragma unroll
        for (int i=0;i<32;i+=4){
            *(float4*)(ud+i) = *(const float4*)(&Ush[row*132+seg*32+i]);
            *(float4*)(md+i) = *(const float4*)(&Msh[row*132+seg*32+i]);
        }
    }
    // P^T[j][m] = gl*delta - sum_t e_t k_t[j] m_t[m];  R[i][j] = sum_t e_t u_t[i] k_t[j]
    const float gl = __expf(lgs[LCH-1]);
    const size_t pbase = ((size_t)(b*NCHUNK + c))*NCC*NCC;
    const int orow = tid >> 1;
    const int ohalf = (tid & 1)*64;
    #pragma unroll
    for (int sub=0; sub<4; sub++){
        float pacc[16];
        #pragma unroll
        for (int i=0;i<16;i++) pacc[i]=0.f;
        const int mb0 = ohalf + sub*16;
        for (int t=0;t<LCH;t++){
            const float sc = esh[t]*Ksh[t*132+orow];
            const float* mr = &Msh[t*132+mb0];
            #pragma unroll
            for (int i=0;i<16;i+=4){
                float4 mv = *(const float4*)(mr+i);
                pacc[i]   -= sc*mv.x; pacc[i+1] -= sc*mv.y;
                pacc[i+2] -= sc*mv.z; pacc[i+3] -= sc*mv.w;
            }
        }
        __bf16* pd = PTb + pbase + (size_t)orow*NCC + mb0;
        #pragma unroll
        for (int i=0;i<16;i++){
            float v = pacc[i];
            if (orow == mb0+i) v += gl;
            pd[i] = (__bf16)v;
        }
    }
    #pragma unroll
    for (int sub=0; sub<4; sub++){
        float racc[16];
        #pragma unroll
        for (int i=0;i<16;i++) racc[i]=0.f;
        const int jb0 = ohalf + sub*16;
        for (int t=0;t<LCH;t++){
            const float sc = esh[t]*Ush[t*132+orow];
            const float* kr = &Ksh[t*132+jb0];
            #pragma unroll
            for (int i=0;i<16;i+=4){
                float4 kv = *(const float4*)(kr+i);
                racc[i]   += sc*kv.x; racc[i+1] += sc*kv.y;
                racc[i+2] += sc*kv.z; racc[i+3] += sc*kv.w;
            }
        }
        float* rd = Rb + pbase + (size_t)orow*NCC + jb0;
        #pragma unroll
        for (int i=0;i<16;i++) rd[i] = racc[i];
    }
}

// ---------------- Phase B: S <- S*P + R over chunks; rows independent ----------------
__global__ __launch_bounds__(256) void k_phaseB(
    const __bf16* __restrict__ PTb, const float* __restrict__ Rb, float* __restrict__ Sb)
{
    __shared__ __attribute__((aligned(16))) float Ssh[16*132];
    const int tid = threadIdx.x;
    const int b = blockIdx.x >> 3, rb = blockIdx.x & 7;
    const int r0 = rb*16;
    const int lane = tid & 63, w = tid >> 6;
    const int q4 = lane >> 4, l16 = lane & 15;
    for (int i=tid; i<16*132; i+=256) Ssh[i] = 0.f;
    __syncthreads();
    for (int c=0; c<NCHUNK; c++){
        const size_t pbase = ((size_t)(b*NCHUNK + c))*NCC*NCC;
        {
            const int row = tid >> 4, cg = (tid & 15)*8;
            float* dst = Sb + pbase + (size_t)(r0+row)*NCC + cg;
            *(float4*)(dst)   = *(const float4*)(&Ssh[row*132+cg]);
            *(float4*)(dst+4) = *(const float4*)(&Ssh[row*132+cg+4]);
        }
        if (c == NCHUNK-1) break;
        v8bf af[4];
        #pragma unroll
        for (int ks=0; ks<4; ks++){
            const float* sr = &Ssh[l16*132 + ks*32 + q4*8];
            v8bf t;
            #pragma unroll
            for (int j=0;j<8;j++) t[j] = (__bf16)sr[j];
            af[ks] = t;
        }
        __syncthreads();
        v4f acc[2] = {};
        #pragma unroll
        for (int nt=0; nt<2; nt++){
            const int n0 = w*32 + nt*16;
            #pragma unroll
            for (int ks=0; ks<4; ks++){
                v8bf bf = *(const v8bf*)(PTb + pbase + (size_t)(n0+l16)*NCC + ks*32 + q4*8);
                acc[nt] = __builtin_amdgcn_mfma_f32_16x16x32_bf16(af[ks], bf, acc[nt], 0,0,0);
            }
        }
        #pragma unroll
        for (int nt=0; nt<2; nt++){
            const int n = w*32 + nt*16 + l16;
            #pragma unroll
            for (int r=0;r<4;r++){
                const int rowl = q4*4 + r;
                Ssh[rowl*132 + n] = acc[nt][r] + Rb[pbase + (size_t)(r0+rowl)*NCC + n];
            }
        }
        __syncthreads();
    }
}

// ---------------- Phase C: per-chunk outputs ----------------
__global__ __launch_bounds__(256) void k_phaseC(
    const float* __restrict__ qb, const float* __restrict__ kb,
    const float* __restrict__ Ub, const float* __restrict__ Mb,
    const float* __restrict__ Sb, const float* __restrict__ lgb,
    float* __restrict__ gb)
{
    __shared__ __attribute__((aligned(16))) float S0T[NCC*132];
    __shared__ __attribute__((aligned(16))) __bf16 Msh[LCH*136];
    __shared__ __attribute__((aligned(16))) __bf16 Qsh[LCH*136];
    __shared__ __attribute__((aligned(16))) __bf16 Ksh[LCH*136];
    __shared__ __attribute__((aligned(16))) __bf16 Wsh[LCH*136];
    __shared__ __attribute__((aligned(16))) float Ash[LCH*68];
    __shared__ float lgs[LCH];

    const int tid = threadIdx.x;
    const int b = blockIdx.x >> 6, c = blockIdx.x & 63;
    const size_t base = (size_t)b*NT + (size_t)c*LCH;
    const size_t pbase = ((size_t)(b*NCHUNK + c))*NCC*NCC;

    {
        const int i = tid >> 1, j0 = (tid & 1)*64;
        const float* src = Sb + pbase + (size_t)i*NCC + j0;
        #pragma unroll 4
        for (int j=0;j<64;j+=4){
            float4 v = *(const float4*)(src+j);
            S0T[(j0+j  )*132 + i] = v.x;
            S0T[(j0+j+1)*132 + i] = v.y;
            S0T[(j0+j+2)*132 + i] = v.z;
            S0T[(j0+j+3)*132 + i] = v.w;
        }
    }
    {
        const int row = tid >> 2, seg = tid & 3;
        const float* ms = Mb + (base+row)*NCC + seg*32;
        const float* qs = qb + (base+row)*NCC + seg*32;
        const float* ks = kb + (base+row)*NCC + seg*32;
        #pragma unroll 8
        for (int i=0;i<32;i++){
            Msh[row*136+seg*32+i] = (__bf16)ms[i];
            Qsh[row*136+seg*32+i] = (__bf16)qs[i];
            Ksh[row*136+seg*32+i] = (__bf16)ks[i];
        }
    }
    if (tid < LCH) lgs[tid] = lgb[base+tid];
    __syncthreads();

    // X1 = M S0^T ; W = U - X1  -> Wsh
    {
        const int tg = tid >> 5, ig = tid & 31;
        float acc[8][4] = {};
        for (int j=0;j<NCC;j++){
            float m8[8];
            #pragma unroll
            for (int r=0;r<8;r++) m8[r] = (float)Msh[(tg*8+r)*136 + j];
            float4 sv = *(const float4*)(&S0T[j*132 + ig*4]);
            #pragma unroll
            for (int r=0;r<8;r++){
                acc[r][0] += m8[r]*sv.x; acc[r][1] += m8[r]*sv.y;
                acc[r][2] += m8[r]*sv.z; acc[r][3] += m8[r]*sv.w;
            }
        }
        #pragma unroll
        for (int r=0;r<8;r++){
            const int t = tg*8+r;
            const float4 uv = *(const float4*)(Ub + (base+t)*NCC + ig*4);
            Wsh[t*136+ig*4+0] = (__bf16)(uv.x - acc[r][0]);
            Wsh[t*136+ig*4+1] = (__bf16)(uv.y - acc[r][1]);
            Wsh[t*136+ig*4+2] = (__bf16)(uv.z - acc[r][2]);
            Wsh[t*136+ig*4+3] = (__bf16)(uv.w - acc[r][3]);
        }
    }
    // O2 = diag(gamma) Q S0 (kept in registers)
    float o2[8][4];
    {
        const int tg = tid >> 5, jg = tid & 31;
        float acc[8][4] = {};
        for (int i=0;i<NCC;i++){
            float q8[8];
            #pragma unroll
            for (int r=0;r<8;r++) q8[r] = (float)Qsh[(tg*8+r)*136 + i];
            float s4[4];
            #pragma unroll
            for (int rr=0;rr<4;rr++) s4[rr] = S0T[(jg+32*rr)*132 + i];
            #pragma unroll
            for (int r=0;r<8;r++){
                acc[r][0] += q8[r]*s4[0]; acc[r][1] += q8[r]*s4[1];
                acc[r][2] += q8[r]*s4[2]; acc[r][3] += q8[r]*s4[3];
            }
        }
        #pragma unroll
        for (int r=0;r<8;r++){
            const float g = __expf(lgs[tg*8+r]);
            #pragma unroll
            for (int d=0;d<4;d++) o2[r][d] = g*acc[r][d];
        }
    }
    __syncthreads();
    // X2 = Q W^T -> A = tril_incl(scaled)
    {
        const int tg2 = tid >> 4, sg = tid & 15;
        float acc[4][4] = {};
        for (int i=0;i<NCC;i++){
            float qv[4], wv[4];
            #pragma unroll
            for (int r=0;r<4;r++){
                qv[r] = (float)Qsh[(tg2+16*r)*136 + i];
                wv[r] = (float)Wsh[(sg+16*r)*136 + i];
            }
            #pragma unroll
            for (int a2=0;a2<4;a2++){
                acc[a2][0] += qv[a2]*wv[0]; acc[a2][1] += qv[a2]*wv[1];
                acc[a2][2] += qv[a2]*wv[2]; acc[a2][3] += qv[a2]*wv[3];
            }
        }
        #pragma unroll
        for (int a2=0;a2<4;a2++){
            const int t = tg2 + 16*a2;
            #pragma unroll
            for (int b2=0;b2<4;b2++){
                const int s = sg + 16*b2;
                Ash[t*68+s] = (s <= t) ? __expf(lgs[t]-lgs[s])*acc[a2][b2] : 0.f;
            }
        }
    }
    __syncthreads();
    // O1 = A K ; o = (O1 + O2) * gate  -> gb (in place)
    {
        const int tg = tid >> 5, jg = tid & 31;
        float acc[8][4] = {};
        for (int s=0;s<LCH;s++){
            float a8[8];
            #pragma unroll
            for (int r=0;r<8;r++) a8[r] = Ash[(tg*8+r)*68 + s];
            float k4[4];
            #pragma unroll
            for (int rr=0;rr<4;rr++) k4[rr] = (float)Ksh[s*136 + jg + 32*rr];
            #pragma unroll
            for (int r=0;r<8;r++){
                acc[r][0] += a8[r]*k4[0]; acc[r][1] += a8[r]*k4[1];
                acc[r][2] += a8[r]*k4[2]; acc[r][3] += a8[r]*k4[3];
            }
        }
        #pragma unroll
        for (int r=0;r<8;r++){
            const int t = tg*8+r;
            #pragma unroll
            for (int d=0;d<4;d++){
                const int j = jg + 32*d;
                const size_t off = (base+t)*NCC + j;
                gb[off] = (acc[r][d] + o2[r][d]) * gb[off];
            }
        }
    }
}

// ---------------- GEMM2: out = obar @ Wo^T + bo ----------------
__global__ __launch_bounds__(256) void k_out(
    const float* __restrict__ ob, const float* __restrict__ Wo,
    const float* __restrict__ bo, float* __restrict__ out)
{
    __shared__ __attribute__((aligned(16))) __bf16 As[128*40];
    __shared__ __attribute__((aligned(16))) __bf16 Bs[64*40];
    const int tid = threadIdx.x;
    const int m0 = blockIdx.x*128, n0 = blockIdx.y*64;
    const int lane = tid & 63, w = tid >> 6;
    const int q4 = lane >> 4, l16 = lane & 15;
    const int arow = tid >> 1, aseg = tid & 1;
    const int brow = tid >> 2, bseg = tid & 3;
    const float* asrc = ob + (size_t)(m0+arow)*NCC;
    const float* bsrc = Wo + (size_t)(n0+brow)*NCC;

    v4f acc[2][4] = {};

    for (int k0=0; k0<NCC; k0+=32){
        __syncthreads();
        {
            float4 f0 = *(const float4*)(asrc + k0 + aseg*16);
            float4 f1 = *(const float4*)(asrc + k0 + aseg*16 + 4);
            float4 f2 = *(const float4*)(asrc + k0 + aseg*16 + 8);
            float4 f3 = *(const float4*)(asrc + k0 + aseg*16 + 12);
            *(v8bf*)(&As[arow*40 + aseg*16])     = pack8(f0,f1);
            *(v8bf*)(&As[arow*40 + aseg*16 + 8]) = pack8(f2,f3);
        }
        {
            float4 g0 = *(const float4*)(bsrc + k0 + bseg*8);
            float4 g1 = *(const float4*)(bsrc + k0 + bseg*8 + 4);
            *(v8bf*)(&Bs[brow*40 + bseg*8]) = pack8(g0,g1);
        }
        __syncthreads();
        v8bf af0 = *(const v8bf*)(&As[(w*32 + l16)*40 + q4*8]);
        v8bf af1 = *(const v8bf*)(&As[(w*32 + 16 + l16)*40 + q4*8]);
        #pragma unroll
        for (int nt=0; nt<4; nt++){
            v8bf bf = *(const v8bf*)(&Bs[(nt*16 + l16)*40 + q4*8]);
            acc[0][nt] = __builtin_amdgcn_mfma_f32_16x16x32_bf16(af0, bf, acc[0][nt], 0,0,0);
            acc[1][nt] = __builtin_amdgcn_mfma_f32_16x16x32_bf16(af1, bf, acc[1][nt], 0,0,0);
        }
    }
    #pragma unroll
    for (int mt=0; mt<2; mt++){
        #pragma unroll
        for (int nt=0; nt<4; nt++){
            const int n = n0 + nt*16 + l16;
            const float bias = bo[n];
            #pragma unroll
            for (int r=0;r<4;r++){
                const int m = m0 + w*32 + mt*16 + q4*4 + r;
                out[(size_t)m*ND + n] = acc[mt][nt][r] + bias;
            }
        }
    }
}

extern "C" void kernel_launch(void* const* d_in, const int* in_sizes, int n_in,
                              void* d_out, int out_size, void* d_ws, size_t ws_size,
                              hipStream_t stream)
{
    const float* x  = (const float*)d_in[0];
    const float* Wq = (const float*)d_in[1];
    const float* bq = (const float*)d_in[2];
    const float* Wk = (const float*)d_in[3];
    const float* bk = (const float*)d_in[4];
    const float* Wv = (const float*)d_in[5];
    const float* bv = (const float*)d_in[6];
    const float* Wa = (const float*)d_in[7];
    const float* ba = (const float*)d_in[8];
    const float* Wb = (const float*)d_in[9];
    const float* bb2= (const float*)d_in[10];
    const float* Wg = (const float*)d_in[11];
    const float* bg = (const float*)d_in[12];
    const float* Wo = (const float*)d_in[13];
    const float* bo = (const float*)d_in[14];

    char* ws = (char*)d_ws;
    const size_t SZ = (size_t)BTROWS*NCC*4;     // 33.55 MB
    float*  qb  = (float*)(ws + 0*SZ);
    float*  kb  = (float*)(ws + 1*SZ);
    float*  vb  = (float*)(ws + 2*SZ);          // v, overwritten by U
    float*  Mb  = (float*)(ws + 3*SZ);
    float*  gb  = (float*)(ws + 4*SZ);          // gate, overwritten by obar
    float*  Sb  = (float*)(ws + 5*SZ);          // 2*SZ: per-chunk incoming states
    float*  Rb  = (float*)(ws + 7*SZ);          // 2*SZ
    __bf16* PTb = (__bf16*)(ws + 9*SZ);         // SZ bytes (bf16)
    float*  ab  = (float*)(ws + 10*SZ);
    float*  beb = (float*)(ws + 10*SZ + 262144);
    float*  lgb = (float*)(ws + 10*SZ + 524288);
    if (ws_size < 10*SZ + 786432) return;       // insufficient workspace

    dim3 blk(256);
    k_proj  <<<dim3(BTROWS/128, 9),  blk, 0, stream>>>(x,Wq,bq,Wk,bk,Wv,bv,Wa,ba,Wb,bb2,Wg,bg,qb,kb,vb,gb,ab,beb);
    k_knorm <<<dim3(BTROWS/4),       blk, 0, stream>>>(kb);
    k_phaseA<<<dim3(NB*NCHUNK),      blk, 0, stream>>>(kb, vb, Mb, ab, beb, lgb, PTb, Rb);
    k_phaseB<<<dim3(NB*8),           blk, 0, stream>>>(PTb, Rb, Sb);
    k_phaseC<<<dim3(NB*NCHUNK),      blk, 0, stream>>>(qb, kb, vb, Mb, Sb, lgb, gb);
    k_out   <<<dim3(BTROWS/128, 16), blk, 0, stream>>>(gb, Wo, bo, (float*)d_out);
}